// Round 14
// baseline (306.905 us; speedup 1.0000x reference)
//
#include <hip/hip_runtime.h>

// out[n] = sum_{e: dst_e = n} (x2[src_e] - x2[dst_e]),  x2 = x @ W   (bias cancels)
// Pipeline (primary): MFMA bf16 GEMM x@W -> x2b (bf16 only);
// deterministic CSR build: per-block bucket hist -> column scan -> bucket scan ->
// exact-offset bin fill -> per-bucket LDS sort (emits per-dst start/cnt);
// gather: one wave per node, src-sum AND self term from bf16 x2b.

#define C_DIM 128
#define EPB 8192          // edges per binning block
#define MAXBK 1024        // max buckets supported by LDS hist (bucket = 128 dsts)

typedef __attribute__((ext_vector_type(8))) short bf16x8;
typedef __attribute__((ext_vector_type(4))) float f32x4;

__device__ __forceinline__ ushort f2b(float f) {   // fp32 -> bf16 RNE
    uint u = __float_as_uint(f);
    u = (u + 0x7FFFu + ((u >> 16) & 1u)) >> 16;
    return (ushort)u;
}
__device__ __forceinline__ float b2f_lo(uint u) { return __uint_as_float(u << 16); }
__device__ __forceinline__ float b2f_hi(uint u) { return __uint_as_float(u & 0xFFFF0000u); }

// ---------------- MFMA GEMM (x2f and x2b both optional) ----------------
__global__ __launch_bounds__(256) void gemm_mfma(const float* __restrict__ x,
                                                 const float* __restrict__ W,
                                                 float* __restrict__ x2f,
                                                 ushort* __restrict__ x2b,
                                                 int nrows) {
    __shared__ ushort Wt[128 * 128];   // 32 KB
    const int tid = threadIdx.x;
    for (int i = tid; i < 4096; i += 256) {
        int k = i >> 5, n0 = (i & 31) * 4;
        float4 w = *(const float4*)(W + k * 128 + n0);
        float wv[4] = {w.x, w.y, w.z, w.w};
#pragma unroll
        for (int j = 0; j < 4; j++) {
            int n = n0 + j;
            Wt[(n * 128 + k) ^ ((n & 7) << 3)] = f2b(wv[j]);
        }
    }
    __syncthreads();

    const int wv_ = tid >> 6;
    const int lane = tid & 63;
    const int ln = lane & 15, kg = lane >> 4;
    const int row_base = blockIdx.x * 128 + wv_ * 32;

    f32x4 acc[2][8];
#pragma unroll
    for (int a = 0; a < 2; a++)
#pragma unroll
        for (int b = 0; b < 8; b++) acc[a][b] = (f32x4)(0.f);

#pragma unroll
    for (int step = 0; step < 4; step++) {
        const int k0 = step * 32 + kg * 8;
        bf16x8 bfr[8];
#pragma unroll
        for (int cf = 0; cf < 8; cf++) {
            int n = cf * 16 + ln;
            bfr[cf] = *(const bf16x8*)&Wt[(n * 128 + k0) ^ ((n & 7) << 3)];
        }
#pragma unroll
        for (int mf = 0; mf < 2; mf++) {
            int row = row_base + mf * 16 + ln;
            bf16x8 afr;
#pragma unroll
            for (int j = 0; j < 8; j++) afr[j] = 0;
            if (row < nrows) {
                const float4* ap = (const float4*)(x + (size_t)row * 128 + k0);
                float4 a0 = ap[0], a1 = ap[1];
                float av[8] = {a0.x, a0.y, a0.z, a0.w, a1.x, a1.y, a1.z, a1.w};
#pragma unroll
                for (int j = 0; j < 8; j++) afr[j] = (short)f2b(av[j]);
            }
#pragma unroll
            for (int cf = 0; cf < 8; cf++)
                acc[mf][cf] = __builtin_amdgcn_mfma_f32_16x16x32_bf16(afr, bfr[cf], acc[mf][cf], 0, 0, 0);
        }
    }

#pragma unroll
    for (int mf = 0; mf < 2; mf++) {
#pragma unroll
        for (int j = 0; j < 4; j++) {
            int row = row_base + mf * 16 + kg * 4 + j;
            if (row >= nrows) continue;
#pragma unroll
            for (int cf = 0; cf < 8; cf++) {
                float v = acc[mf][cf][j];
                int col = cf * 16 + ln;
                if (x2f) x2f[(size_t)row * 128 + col] = v;
                if (x2b) x2b[(size_t)row * 128 + col] = f2b(v);
            }
        }
    }
}

// ---------------- helpers ----------------
__global__ __launch_bounds__(256) void zero_ints(int* p, int n) {
    int i = blockIdx.x * 256 + threadIdx.x;
    if (i < n) p[i] = 0;
}

// ---------------- deterministic bucket CSR build ----------------
// Pass 1: per-block bucket histogram -> gbh[block][bucket] (coalesced row write).
__global__ __launch_bounds__(256) void bucket_hist2(const int* __restrict__ ei,
                                                    int* __restrict__ gbh,
                                                    int ne, int nn, int nbk) {
    __shared__ int hist[MAXBK];
    const int e0 = blockIdx.x * EPB;
    const int e1 = min(ne, e0 + EPB);
    for (int i = threadIdx.x; i < nbk; i += 256) hist[i] = 0;
    __syncthreads();
    for (int e = e0 + threadIdx.x; e < e1; e += 256) {
        int dst = ei[e];
        if ((unsigned)dst < (unsigned)nn) atomicAdd(&hist[dst >> 7], 1);
    }
    __syncthreads();
    int* row = gbh + (size_t)blockIdx.x * nbk;
    for (int i = threadIdx.x; i < nbk; i += 256) row[i] = hist[i];
}

// Pass 2: column-wise exclusive scan of gbh over blocks; emits per-bucket totals.
// thread t of block b handles bucket i = b*256+t; reads/writes are coalesced.
__global__ __launch_bounds__(256) void bucket_colscan(int* __restrict__ gbh,
                                                      int* __restrict__ tot,
                                                      int nbk, int nblk) {
    int i = blockIdx.x * 256 + threadIdx.x;
    if (i >= nbk) return;
    int run = 0;
    for (int b = 0; b < nblk; b++) {
        size_t idx = (size_t)b * nbk + i;
        int v = gbh[idx];
        gbh[idx] = run;
        run += v;
    }
    tot[i] = run;
}

// Pass 3: single-block exclusive scan tot[nbk] -> bstart[nbk+1].
__global__ __launch_bounds__(1024) void bucket_scan(const int* __restrict__ tot,
                                                    int* __restrict__ bstart, int nbk) {
    __shared__ int s[1024];
    int v = (threadIdx.x < nbk) ? tot[threadIdx.x] : 0;
    s[threadIdx.x] = v;
    __syncthreads();
    for (int off = 1; off < 1024; off <<= 1) {
        int t = (threadIdx.x >= off) ? s[threadIdx.x - off] : 0;
        __syncthreads();
        s[threadIdx.x] += t;
        __syncthreads();
    }
    if (threadIdx.x < nbk) {
        bstart[threadIdx.x] = s[threadIdx.x] - v;   // exclusive
        if (threadIdx.x == nbk - 1) bstart[nbk] = s[threadIdx.x];
    }
}

// Pass 4: exact-offset bin fill — no global atomics, single edge pass.
__global__ __launch_bounds__(256) void bin_edges3(const int* __restrict__ ei,
                                                  const int* __restrict__ bstart,
                                                  const int* __restrict__ gbh,
                                                  uint* __restrict__ bbuf,
                                                  int ne, int nn, int nbk) {
    __shared__ int base[MAXBK];
    __shared__ int h[MAXBK];
    const int e0 = blockIdx.x * EPB;
    const int e1 = min(ne, e0 + EPB);
    const int* row = gbh + (size_t)blockIdx.x * nbk;
    for (int i = threadIdx.x; i < nbk; i += 256) {
        base[i] = bstart[i] + row[i];
        h[i] = 0;
    }
    __syncthreads();
    for (int e = e0 + threadIdx.x; e < e1; e += 256) {
        int dst = ei[e];
        int src = ei[ne + e];
        if ((unsigned)dst >= (unsigned)nn || (unsigned)src >= (unsigned)nn) continue;
        int b = dst >> 7;
        int r = atomicAdd(&h[b], 1);
        bbuf[base[b] + r] = ((uint)(dst & 127) << 17) | (uint)src;
    }
}

// Pass 5: one block per bucket — LDS hist over 128 dsts, LDS scan, emit per-dst
// start/cnt to global, then counting-rank scatter src into exact CSR slots.
__global__ __launch_bounds__(256) void sort_bucket2(const uint* __restrict__ bbuf,
                                                    const int* __restrict__ bstart,
                                                    int* __restrict__ csr,
                                                    int* __restrict__ start,
                                                    int* __restrict__ cnt, int n) {
    __shared__ int h[128];    // hist, then rank counter
    __shared__ int sb[128];   // scan buffer -> per-dst global base
    const int b = blockIdx.x;
    const int d0 = b << 7;
    const int base = bstart[b];
    const int end = bstart[b + 1];
    if (threadIdx.x < 128) h[threadIdx.x] = 0;
    __syncthreads();
    for (int i = base + threadIdx.x; i < end; i += 256)
        atomicAdd(&h[bbuf[i] >> 17], 1);
    __syncthreads();
    if (threadIdx.x < 128) sb[threadIdx.x] = h[threadIdx.x];
    __syncthreads();
    for (int off = 1; off < 128; off <<= 1) {
        int t = 0;
        if (threadIdx.x < 128 && threadIdx.x >= off) t = sb[threadIdx.x - off];
        __syncthreads();
        if (threadIdx.x < 128) sb[threadIdx.x] += t;
        __syncthreads();
    }
    if (threadIdx.x < 128) {
        int excl = sb[threadIdx.x] - h[threadIdx.x];   // exclusive scan value
        int gbase = base + excl;
        sb[threadIdx.x] = gbase;
        int d = d0 + threadIdx.x;
        if (d < n) { start[d] = gbase; cnt[d] = h[threadIdx.x]; }
        h[threadIdx.x] = 0;   // reuse as rank
    }
    __syncthreads();
    for (int i = base + threadIdx.x; i < end; i += 256) {
        uint p = bbuf[i];
        int d7 = (int)(p >> 17);
        int src = (int)(p & 0x1FFFFu);
        int r = atomicAdd(&h[d7], 1);
        csr[sb[d7] + r] = src;
    }
}

// ---------------- gather: all-bf16 (src sum + self term), one wave per node ----------------
__global__ __launch_bounds__(256) void gather_b16b(const int* __restrict__ csr,
                                                   const int* __restrict__ start,
                                                   const int* __restrict__ cnt,
                                                   const uint* __restrict__ x2b,
                                                   float* __restrict__ out, int nn) {
    int wave = (int)((blockIdx.x * 256 + threadIdx.x) >> 6);
    int lane = threadIdx.x & 63;
    if (wave >= nn) return;
    const int s0 = start[wave];
    const int dg = cnt[wave];
    float a0 = 0, a1 = 0, b0 = 0, b1 = 0, c0 = 0, c1 = 0, d0 = 0, d1 = 0;
    int e = 0;
    for (; e + 4 <= dg; e += 4) {
        int s1 = csr[s0 + e], s2 = csr[s0 + e + 1];
        int s3 = csr[s0 + e + 2], s4 = csr[s0 + e + 3];
        uint u1 = x2b[(size_t)s1 * 64 + lane];
        uint u2 = x2b[(size_t)s2 * 64 + lane];
        uint u3 = x2b[(size_t)s3 * 64 + lane];
        uint u4 = x2b[(size_t)s4 * 64 + lane];
        a0 += b2f_lo(u1); a1 += b2f_hi(u1);
        b0 += b2f_lo(u2); b1 += b2f_hi(u2);
        c0 += b2f_lo(u3); c1 += b2f_hi(u3);
        d0 += b2f_lo(u4); d1 += b2f_hi(u4);
    }
    for (; e < dg; e++) {
        int s1 = csr[s0 + e];
        uint u1 = x2b[(size_t)s1 * 64 + lane];
        a0 += b2f_lo(u1); a1 += b2f_hi(u1);
    }
    uint us = x2b[(size_t)wave * 64 + lane];
    float d = (float)dg;
    float2 o;
    o.x = (a0 + b0) + (c0 + d0) - d * b2f_lo(us);
    o.y = (a1 + b1) + (c1 + d1) - d * b2f_hi(us);
    ((float2*)out)[(size_t)wave * 64 + lane] = o;
}

// ---------------- fallback path kernels (ws too small / too many buckets) ----------------
__global__ __launch_bounds__(256) void count_deg(const int* __restrict__ ei,
                                                 int* __restrict__ cnt, int ne, int nn) {
    int e = blockIdx.x * 256 + threadIdx.x;
    if (e >= ne) return;
    int dst = ei[e];
    if ((unsigned)dst < (unsigned)nn) atomicAdd(&cnt[dst], 1);
}

__global__ __launch_bounds__(256) void scan_partials(const int* __restrict__ cnt,
                                                     int* __restrict__ bsum, int n) {
    __shared__ int red[256];
    int i = blockIdx.x * 1024 + threadIdx.x * 4;
    int s = 0;
    if (i + 3 < n) {
        int4 v = *(const int4*)(cnt + i);
        s = v.x + v.y + v.z + v.w;
    } else {
        for (int j = i; j < n && j < i + 4; j++) s += cnt[j];
    }
    red[threadIdx.x] = s;
    __syncthreads();
    for (int off = 128; off > 0; off >>= 1) {
        if (threadIdx.x < off) red[threadIdx.x] += red[threadIdx.x + off];
        __syncthreads();
    }
    if (threadIdx.x == 0) bsum[blockIdx.x] = red[0];
}

__global__ __launch_bounds__(1024) void scan_bsums(int* __restrict__ bsum, int nb) {
    __shared__ int s[1024];
    int v = (threadIdx.x < nb) ? bsum[threadIdx.x] : 0;
    s[threadIdx.x] = v;
    __syncthreads();
    for (int off = 1; off < 1024; off <<= 1) {
        int t = (threadIdx.x >= off) ? s[threadIdx.x - off] : 0;
        __syncthreads();
        s[threadIdx.x] += t;
        __syncthreads();
    }
    if (threadIdx.x < nb) bsum[threadIdx.x] = s[threadIdx.x] - v;  // exclusive
}

__global__ __launch_bounds__(256) void scan_apply(const int* __restrict__ cnt,
                                                  const int* __restrict__ bsum,
                                                  int* __restrict__ start,
                                                  int* __restrict__ next, int n) {
    __shared__ int s[256];
    int i = blockIdx.x * 1024 + threadIdx.x * 4;
    int4 v = make_int4(0, 0, 0, 0);
    if (i + 3 < n) {
        v = *(const int4*)(cnt + i);
    } else {
        if (i + 0 < n) v.x = cnt[i + 0];
        if (i + 1 < n) v.y = cnt[i + 1];
        if (i + 2 < n) v.z = cnt[i + 2];
        if (i + 3 < n) v.w = cnt[i + 3];
    }
    int tsum = v.x + v.y + v.z + v.w;
    s[threadIdx.x] = tsum;
    __syncthreads();
    for (int off = 1; off < 256; off <<= 1) {
        int t = (threadIdx.x >= off) ? s[threadIdx.x - off] : 0;
        __syncthreads();
        s[threadIdx.x] += t;
        __syncthreads();
    }
    int r0 = s[threadIdx.x] - tsum + bsum[blockIdx.x];
    int r1 = r0 + v.x, r2 = r1 + v.y, r3 = r2 + v.z;
    if (i + 3 < n) {
        *(int4*)(start + i) = make_int4(r0, r1, r2, r3);
        *(int4*)(next + i) = make_int4(r0, r1, r2, r3);
    } else {
        int rr[4] = {r0, r1, r2, r3};
        for (int j = 0; j < 4 && i + j < n; j++) {
            start[i + j] = rr[j];
            next[i + j] = rr[j];
        }
    }
}

__global__ __launch_bounds__(256) void fill_csr(const int* __restrict__ ei,
                                                int* __restrict__ next,
                                                int* __restrict__ csr, int ne, int nn) {
    int e = blockIdx.x * 256 + threadIdx.x;
    if (e >= ne) return;
    int dst = ei[e];
    int src = ei[ne + e];
    if ((unsigned)dst >= (unsigned)nn || (unsigned)src >= (unsigned)nn) return;
    int slot = atomicAdd(&next[dst], 1);
    csr[slot] = src;
}

// fp32 fallback gather
__global__ __launch_bounds__(256) void gather_out(const int* __restrict__ csr,
                                                  const int* __restrict__ start,
                                                  const int* __restrict__ cnt,
                                                  const float* __restrict__ x2,
                                                  float* __restrict__ out, int nn) {
    int wave = (int)((blockIdx.x * 256 + threadIdx.x) >> 6);
    int lane = threadIdx.x & 63;
    if (wave >= nn) return;
    const int s0 = start[wave];
    const int dg = cnt[wave];
    const float2* __restrict__ base = (const float2*)x2;
    float2 acc0 = make_float2(0.f, 0.f), acc1 = make_float2(0.f, 0.f);
    int e = 0;
    for (; e + 2 <= dg; e += 2) {
        int s1 = csr[s0 + e], s2 = csr[s0 + e + 1];
        float2 v1 = base[(size_t)s1 * 64 + lane];
        float2 v2 = base[(size_t)s2 * 64 + lane];
        acc0.x += v1.x; acc0.y += v1.y;
        acc1.x += v2.x; acc1.y += v2.y;
    }
    if (e < dg) {
        int s1 = csr[s0 + e];
        float2 v1 = base[(size_t)s1 * 64 + lane];
        acc0.x += v1.x; acc0.y += v1.y;
    }
    float2 self = base[(size_t)wave * 64 + lane];
    float d = (float)dg;
    float2 o;
    o.x = acc0.x + acc1.x - d * self.x;
    o.y = acc0.y + acc1.y - d * self.y;
    ((float2*)out)[(size_t)wave * 64 + lane] = o;
}

extern "C" void kernel_launch(void* const* d_in, const int* in_sizes, int n_in,
                              void* d_out, int out_size, void* d_ws, size_t ws_size,
                              hipStream_t stream) {
    const float* x = (const float*)d_in[0];
    const int* ei = (const int*)d_in[1];
    const float* W = (const float*)d_in[2];
    // d_in[3] (bias) provably unused: cancels in out = A@x2 - x2*deg.
    float* out = (float*)d_out;

    const int n = in_sizes[0] / C_DIM;     // 100000
    const int ne = in_sizes[1] / 2;        // 1600000
    const int nbk = (n + 127) / 128;       // buckets of 128 dsts (782)
    const int nb = (n + 1023) / 1024;      // fallback scan tiles
    const int binblocks = (ne + EPB - 1) / EPB;   // 196

    const size_t sz_x2f = (size_t)n * C_DIM * sizeof(float);
    const size_t sz_x2b = (size_t)n * C_DIM * sizeof(ushort);
    const size_t sz_int = (size_t)n * sizeof(int);
    const size_t sz_bkt = (size_t)((nbk + 4) & ~3) * sizeof(int);  // nbk(+1) ints padded
    const size_t sz_gbh = (size_t)binblocks * nbk * sizeof(int);
    const size_t sz_e = (size_t)ne * sizeof(int);
    const size_t sz_bs = (size_t)((nb + 3) & ~3) * sizeof(int);
    const size_t need_bin = sz_x2b + 2 * sz_int + 2 * sz_bkt + sz_gbh + 2 * sz_e;
    const size_t need_f32 = sz_x2f + 3 * sz_int + sz_bs + sz_e;
    const bool use_bin = ws_size >= need_bin && nbk <= MAXBK && n < (1 << 17);

    char* ws = (char*)d_ws;

    if (use_bin) {
        ushort* x2b = (ushort*)ws;          ws += sz_x2b;
        int* cnt = (int*)ws;                ws += sz_int;
        int* start = (int*)ws;              ws += sz_int;
        int* bstart = (int*)ws;             ws += sz_bkt;   // nbk+1 entries
        int* tot = (int*)ws;                ws += sz_bkt;
        int* gbh = (int*)ws;                ws += sz_gbh;
        int* csr = (int*)ws;                ws += sz_e;
        uint* bbuf = (uint*)ws;

        int ntiles = (n + 127) / 128;
        gemm_mfma<<<ntiles, 256, 0, stream>>>(x, W, nullptr, x2b, n);

        bucket_hist2<<<binblocks, 256, 0, stream>>>(ei, gbh, ne, n, nbk);
        bucket_colscan<<<(nbk + 255) / 256, 256, 0, stream>>>(gbh, tot, nbk, binblocks);
        bucket_scan<<<1, 1024, 0, stream>>>(tot, bstart, nbk);
        bin_edges3<<<binblocks, 256, 0, stream>>>(ei, bstart, gbh, bbuf, ne, n, nbk);
        sort_bucket2<<<nbk, 256, 0, stream>>>(bbuf, bstart, csr, start, cnt, n);

        int gblocks = (n + 3) / 4;   // 4 waves per block, 1 node per wave
        gather_b16b<<<gblocks, 256, 0, stream>>>(csr, start, cnt, (const uint*)x2b, out, n);
    } else {
        float* x2f = (float*)ws;            ws += sz_x2f;
        int* cnt = (int*)ws;                ws += sz_int;
        int* start = (int*)ws;              ws += sz_int;
        int* bsum = (int*)ws;               ws += sz_bs;
        int* next = (int*)ws;               ws += sz_int;
        int* csr = (int*)ws;
        (void)need_f32;

        zero_ints<<<(n + 255) / 256, 256, 0, stream>>>(cnt, n);
        int ntiles = (n + 127) / 128;
        gemm_mfma<<<ntiles, 256, 0, stream>>>(x, W, x2f, nullptr, n);
        int eblocks = (ne + 255) / 256;
        count_deg<<<eblocks, 256, 0, stream>>>(ei, cnt, ne, n);
        scan_partials<<<nb, 256, 0, stream>>>(cnt, bsum, n);
        scan_bsums<<<1, 1024, 0, stream>>>(bsum, nb);
        scan_apply<<<nb, 256, 0, stream>>>(cnt, bsum, start, next, n);
        fill_csr<<<eblocks, 256, 0, stream>>>(ei, next, csr, ne, n);
        int gblocks = (n + 3) / 4;
        gather_out<<<gblocks, 256, 0, stream>>>(csr, start, cnt, x2f, out, n);
    }
}